// Round 1
// 605.849 us; speedup vs baseline: 1.3614x; 1.3614x over previous
//
#include <hip/hip_runtime.h>

#define DIM 128

using f16 = _Float16;
using f16x4 = __attribute__((ext_vector_type(4))) f16;

// ---------------- CSR build ----------------

// deg[v] = number of directed edges with destination v
__global__ void k_count(const int* __restrict__ u_idx, const int* __restrict__ i_idx,
                        int E, int n_u, int* __restrict__ deg) {
    int i = blockIdx.x * blockDim.x + threadIdx.x;
    int stride = gridDim.x * blockDim.x;
    int total = 2 * E;
    for (; i < total; i += stride) {
        if (i < E) atomicAdd(&deg[u_idx[i]], 1);
        else       atomicAdd(&deg[n_u + i_idx[i - E]], 1);
    }
}

__global__ void k_rnorm(const int* __restrict__ deg, float* __restrict__ rnorm, int n) {
    int i = blockIdx.x * blockDim.x + threadIdx.x;
    int stride = gridDim.x * blockDim.x;
    for (; i < n; i += stride) {
        int d = deg[i];
        // reference deg = 2*d (bincount over [r,c]); rows with d==0 never feed edges
        rnorm[i] = (d > 0) ? rsqrtf(2.0f * (float)d) : 0.0f;
    }
}

// fp16 pre-scaled gather source: xh[v] = fp16(rnorm[v] * x0[v])
__global__ void k_scale_h(const float* __restrict__ u_emb, const float* __restrict__ i_emb,
                          const float* __restrict__ rnorm, int n_u, int n,
                          f16* __restrict__ xh) {
    int g = blockIdx.x * blockDim.x + threadIdx.x;
    int stride = gridDim.x * blockDim.x;
    int total = n * 32;
    for (; g < total; g += stride) {
        int v = g >> 5;
        int lane = g & 31;
        const float* src = (v < n_u) ? (u_emb + (size_t)v * DIM)
                                     : (i_emb + (size_t)(v - n_u) * DIM);
        float r = rnorm[v];
        float4 x = *reinterpret_cast<const float4*>(src + lane * 4);
        f16x4 o;
        o[0] = (f16)(x.x * r);
        o[1] = (f16)(x.y * r);
        o[2] = (f16)(x.z * r);
        o[3] = (f16)(x.w * r);
        *reinterpret_cast<f16x4*>(xh + (size_t)v * DIM + lane * 4) = o;
    }
}

// exclusive scan over deg (3 kernels, n up to 512*1024)
__global__ void k_scan1(const int* __restrict__ deg, int n, int* __restrict__ partials) {
    __shared__ int sh[256];
    int tid = threadIdx.x;
    int base = blockIdx.x * 1024 + tid * 4;
    int s = 0;
#pragma unroll
    for (int j = 0; j < 4; ++j) {
        int idx = base + j;
        if (idx < n) s += deg[idx];
    }
    sh[tid] = s;
    __syncthreads();
    for (int off = 128; off > 0; off >>= 1) {
        if (tid < off) sh[tid] += sh[tid + off];
        __syncthreads();
    }
    if (tid == 0) partials[blockIdx.x] = sh[0];
}

__global__ void k_scan2(const int* __restrict__ partials, int* __restrict__ offsets, int NB) {
    __shared__ int sh[512];
    int tid = threadIdx.x;
    int v = (tid < NB) ? partials[tid] : 0;
    sh[tid] = v;
    __syncthreads();
    for (int off = 1; off < 512; off <<= 1) {
        int t = (tid >= off) ? sh[tid - off] : 0;
        __syncthreads();
        sh[tid] += t;
        __syncthreads();
    }
    if (tid < NB) offsets[tid] = sh[tid] - v;  // exclusive
}

__global__ void k_scan3(const int* __restrict__ deg, int n,
                        const int* __restrict__ offsets, int* __restrict__ row_ptr, int twoE) {
    __shared__ int sh[256];
    int tid = threadIdx.x;
    int base = blockIdx.x * 1024 + tid * 4;
    int v[4];
    int ts = 0;
#pragma unroll
    for (int j = 0; j < 4; ++j) {
        int idx = base + j;
        v[j] = (idx < n) ? deg[idx] : 0;
        ts += v[j];
    }
    sh[tid] = ts;
    __syncthreads();
    for (int off = 1; off < 256; off <<= 1) {
        int t = (tid >= off) ? sh[tid - off] : 0;
        __syncthreads();
        sh[tid] += t;
        __syncthreads();
    }
    int run = sh[tid] - ts + offsets[blockIdx.x];
#pragma unroll
    for (int j = 0; j < 4; ++j) {
        int idx = base + j;
        if (idx < n) row_ptr[idx] = run;
        run += v[j];
    }
    if (blockIdx.x == 0 && tid == 0) row_ptr[n] = twoE;
}

// adjacency fill (no weights — weights folded into fp16 source / rnorm gathers)
__global__ void k_fill(const int* __restrict__ u_idx, const int* __restrict__ i_idx,
                       int E, int n_u, const int* __restrict__ row_ptr,
                       int* __restrict__ cursor, int* __restrict__ adj) {
    int i = blockIdx.x * blockDim.x + threadIdx.x;
    int stride = gridDim.x * blockDim.x;
    int total = 2 * E;
    for (; i < total; i += stride) {
        int r, c;
        if (i < E) { r = u_idx[i];            c = n_u + i_idx[i]; }
        else       { int t = i - E; r = n_u + i_idx[t]; c = u_idx[t]; }
        int pos = atomicAdd(&cursor[r], 1);
        adj[row_ptr[r] + pos] = c;
    }
}

// ---------------- SpMM ----------------
// One 32-lane half-wave per row; 4 fp16 elements (8B) per lane (128 = 32*4).
// MODE 0: gather source xh is pre-scaled by rnorm[c] (weight 1); writes
//         yh[row] = fp16(rnorm[row] * sum)          (= x1, plain, fp16)
// MODE 1: gather source xh is plain x1 (fp16); per-edge weight rnorm[c];
//         writes y[row] = (x0 + x1 + rnorm[row]*sum)/3  (fused final combine)
// Tail is predicated with clamped indices so 4 gathers stay in flight
// (clamped duplicates hit the just-fetched L1 line — free).

template <int MODE>
__global__ __launch_bounds__(256) void k_spmm(const int* __restrict__ row_ptr,
                                              const int* __restrict__ adj,
                                              const float* __restrict__ rnorm,
                                              const f16* __restrict__ xh,
                                              const float* __restrict__ u_emb,
                                              const float* __restrict__ i_emb,
                                              int n_u, int n,
                                              float* __restrict__ y,
                                              f16* __restrict__ yh) {
    int g = blockIdx.x * blockDim.x + threadIdx.x;
    int row = g >> 5;
    int lane = g & 31;
    if (row >= n) return;
    int s = row_ptr[row];
    int e = row_ptr[row + 1];
    float rnr = rnorm[row];
    float4 acc = make_float4(0.f, 0.f, 0.f, 0.f);
    const f16* xb = xh + lane * 4;
    for (int k = s; k < e; k += 4) {
        int e1 = e - 1;
        int k1 = k + 1, k2 = k + 2, k3 = k + 3;
        int c0 = adj[k];
        int c1 = adj[(k1 <= e1) ? k1 : e1];
        int c2 = adj[(k2 <= e1) ? k2 : e1];
        int c3 = adj[(k3 <= e1) ? k3 : e1];
        float w0, w1, w2, w3;
        if (MODE == 1) {
            w0 = rnorm[c0];
            w1 = (k1 < e) ? rnorm[c1] : 0.f;
            w2 = (k2 < e) ? rnorm[c2] : 0.f;
            w3 = (k3 < e) ? rnorm[c3] : 0.f;
        } else {
            w0 = 1.f;
            w1 = (k1 < e) ? 1.f : 0.f;
            w2 = (k2 < e) ? 1.f : 0.f;
            w3 = (k3 < e) ? 1.f : 0.f;
        }
        f16x4 v0 = *reinterpret_cast<const f16x4*>(xb + (size_t)c0 * DIM);
        f16x4 v1 = *reinterpret_cast<const f16x4*>(xb + (size_t)c1 * DIM);
        f16x4 v2 = *reinterpret_cast<const f16x4*>(xb + (size_t)c2 * DIM);
        f16x4 v3 = *reinterpret_cast<const f16x4*>(xb + (size_t)c3 * DIM);
        acc.x = fmaf((float)v0[0], w0, acc.x);
        acc.y = fmaf((float)v0[1], w0, acc.y);
        acc.z = fmaf((float)v0[2], w0, acc.z);
        acc.w = fmaf((float)v0[3], w0, acc.w);
        acc.x = fmaf((float)v1[0], w1, acc.x);
        acc.y = fmaf((float)v1[1], w1, acc.y);
        acc.z = fmaf((float)v1[2], w1, acc.z);
        acc.w = fmaf((float)v1[3], w1, acc.w);
        acc.x = fmaf((float)v2[0], w2, acc.x);
        acc.y = fmaf((float)v2[1], w2, acc.y);
        acc.z = fmaf((float)v2[2], w2, acc.z);
        acc.w = fmaf((float)v2[3], w2, acc.w);
        acc.x = fmaf((float)v3[0], w3, acc.x);
        acc.y = fmaf((float)v3[1], w3, acc.y);
        acc.z = fmaf((float)v3[2], w3, acc.z);
        acc.w = fmaf((float)v3[3], w3, acc.w);
    }
    acc.x *= rnr; acc.y *= rnr; acc.z *= rnr; acc.w *= rnr;
    if (MODE == 0) {
        f16x4 h;
        h[0] = (f16)acc.x;
        h[1] = (f16)acc.y;
        h[2] = (f16)acc.z;
        h[3] = (f16)acc.w;
        *reinterpret_cast<f16x4*>(yh + (size_t)row * DIM + lane * 4) = h;
    } else {
        const float* x0b = (row < n_u) ? (u_emb + (size_t)row * DIM)
                                       : (i_emb + (size_t)(row - n_u) * DIM);
        float4 x0 = *reinterpret_cast<const float4*>(x0b + lane * 4);
        f16x4 a1 = *reinterpret_cast<const f16x4*>(xh + (size_t)row * DIM + lane * 4);
        const float third = 1.0f / 3.0f;
        float4 o;
        o.x = (x0.x + (float)a1[0] + acc.x) * third;
        o.y = (x0.y + (float)a1[1] + acc.y) * third;
        o.z = (x0.z + (float)a1[2] + acc.z) * third;
        o.w = (x0.w + (float)a1[3] + acc.w) * third;
        *reinterpret_cast<float4*>(y + (size_t)row * DIM + lane * 4) = o;
    }
}

// ---------------- host ----------------

static inline int grid_for(long long work, int block, int cap = 4096) {
    long long b = (work + block - 1) / block;
    if (b > cap) b = cap;
    if (b < 1) b = 1;
    return (int)b;
}

extern "C" void kernel_launch(void* const* d_in, const int* in_sizes, int n_in,
                              void* d_out, int out_size, void* d_ws, size_t ws_size,
                              hipStream_t stream) {
    const float* u_emb = (const float*)d_in[0];
    const float* i_emb = (const float*)d_in[1];
    const int* u_idx = (const int*)d_in[2];
    const int* i_idx = (const int*)d_in[3];

    const int n_u = in_sizes[0] / DIM;
    const int n_i = in_sizes[1] / DIM;
    const int n = n_u + n_i;
    const int E = in_sizes[2];
    const int twoE = 2 * E;
    const int NB = (n + 1023) / 1024;  // scan blocks (<= 512)

    // workspace layout
    char* w = (char*)d_ws;
    auto alloc = [&](size_t bytes) -> void* {
        void* p = (void*)w;
        w += (bytes + 255) & ~(size_t)255;
        return p;
    };
    f16*   xh0     = (f16*)alloc((size_t)n * DIM * sizeof(f16));  // rnorm-scaled x0, fp16
    f16*   xh1     = (f16*)alloc((size_t)n * DIM * sizeof(f16));  // plain x1, fp16
    float* rnorm   = (float*)alloc((size_t)n * sizeof(float));
    int*   deg     = (int*)alloc((size_t)n * sizeof(int));
    int*   cursor  = (int*)alloc((size_t)n * sizeof(int));
    int*   row_ptr = (int*)alloc((size_t)(n + 1) * sizeof(int));
    int*   adj     = (int*)alloc((size_t)twoE * sizeof(int));
    int*   parts   = (int*)alloc((size_t)NB * sizeof(int));
    int*   offs    = (int*)alloc((size_t)NB * sizeof(int));
    (void)ws_size;

    hipMemsetAsync(deg, 0, (size_t)n * sizeof(int), stream);
    hipMemsetAsync(cursor, 0, (size_t)n * sizeof(int), stream);

    k_count<<<grid_for(twoE, 256, 2048), 256, 0, stream>>>(u_idx, i_idx, E, n_u, deg);
    k_rnorm<<<grid_for(n, 256), 256, 0, stream>>>(deg, rnorm, n);
    k_scale_h<<<grid_for((long long)n * 32, 256, 8192), 256, 0, stream>>>(u_emb, i_emb, rnorm,
                                                                          n_u, n, xh0);
    k_scan1<<<NB, 256, 0, stream>>>(deg, n, parts);
    k_scan2<<<1, 512, 0, stream>>>(parts, offs, NB);
    k_scan3<<<NB, 256, 0, stream>>>(deg, n, offs, row_ptr, twoE);
    k_fill<<<grid_for(twoE, 256, 2048), 256, 0, stream>>>(u_idx, i_idx, E, n_u, row_ptr,
                                                          cursor, adj);

    int sblocks = (int)(((long long)n * 32 + 255) / 256);
    // layer 1: xh1 = fp16( rnorm * (A_unw @ xh0) )   (xh0 pre-scaled by rnorm)
    k_spmm<0><<<sblocks, 256, 0, stream>>>(row_ptr, adj, rnorm, xh0, nullptr, nullptr,
                                           n_u, n, nullptr, xh1);
    // layer 2 + fused combine: out = (x0 + x1 + rnorm*(A_unw @ (rnorm .* x1)))/3
    k_spmm<1><<<sblocks, 256, 0, stream>>>(row_ptr, adj, rnorm, xh1, u_emb, i_emb,
                                           n_u, n, (float*)d_out, nullptr);
}